// Round 8
// baseline (344.927 us; speedup 1.0000x reference)
//
#include <hip/hip_runtime.h>

#define DEVFN __device__ __forceinline__

typedef __attribute__((ext_vector_type(8))) short bf16x8;
typedef __attribute__((ext_vector_type(4))) float f32x4;
typedef __attribute__((ext_vector_type(16))) float f32x16;

#define MFMA16(a, b, c) __builtin_amdgcn_mfma_f32_16x16x32_bf16(a, b, c, 0, 0, 0)
#define MFMA32(a, b, c) __builtin_amdgcn_mfma_f32_32x32x16_bf16(a, b, c, 0, 0, 0)

DEVFN unsigned short f2bf(float f) {
  union { float f; unsigned u; } v; v.f = f;
  unsigned r = v.u + 0x7FFFu + ((v.u >> 16) & 1u);
  return (unsigned short)(r >> 16);
}
DEVFN unsigned pack2bf(float a, float b) {
  return (unsigned)f2bf(a) | ((unsigned)f2bf(b) << 16);
}
DEVFN unsigned cvtpk(float lo, float hi) {
  unsigned r;
  asm("v_cvt_pk_bf16_f32 %0, %1, %2" : "=v"(r) : "v"(lo), "v"(hi));
  return r;
}
DEVFN void pl32swap(unsigned& a, unsigned& b) {
  asm("v_permlane32_swap_b32 %0, %1" : "+v"(a), "+v"(b));
}
DEVFN void gll16(const void* g, void* l) {
  __builtin_amdgcn_global_load_lds((__attribute__((address_space(1))) void*)g,
                                   (__attribute__((address_space(3))) void*)l,
                                   16, 0, 0);
}

// ---------------- precompute kernels ----------------

__global__ __launch_bounds__(256) void conv_x_k(const float* __restrict__ x,
                                                unsigned short* __restrict__ xb) {
  int i = (blockIdx.x * 256 + threadIdx.x) * 4;
  float4 v = *(const float4*)(x + i);
  uint2 u;
  u.x = pack2bf(v.x, v.y);
  u.y = pack2bf(v.z, v.w);
  *(uint2*)(xb + i) = u;
}

// WT[n][k] = (bf16) W[k][n], 64x64 tiles through LDS
__global__ __launch_bounds__(256) void transp_k(
    const float* __restrict__ Wq, const float* __restrict__ Wk,
    const float* __restrict__ Wv, const float* __restrict__ Wo,
    unsigned short* __restrict__ Tq, unsigned short* __restrict__ Tk,
    unsigned short* __restrict__ Tv, unsigned short* __restrict__ To) {
  __shared__ unsigned short t[64 * 65];
  int z = blockIdx.z;
  const float* src = (z == 0) ? Wq : (z == 1) ? Wk : (z == 2) ? Wv : Wo;
  unsigned short* dst = (z == 0) ? Tq : (z == 1) ? Tk : (z == 2) ? Tv : To;
  int k0 = blockIdx.x * 64, n0 = blockIdx.y * 64;
  int tid = threadIdx.x;
#pragma unroll
  for (int i = 0; i < 16; ++i) {
    int flat = i * 256 + tid;
    int r = flat >> 6, cc = flat & 63;
    t[cc * 65 + r] = f2bf(src[(size_t)(k0 + r) * 1024 + n0 + cc]);
  }
  __syncthreads();
#pragma unroll
  for (int i = 0; i < 16; ++i) {
    int flat = i * 256 + tid;
    int rr = flat >> 6, cc = flat & 63;
    dst[(size_t)(n0 + rr) * 1024 + k0 + cc] = t[rr * 65 + cc];
  }
}

__global__ __launch_bounds__(256) void rope_k(float2* __restrict__ rtab) {
  int idx = blockIdx.x * 256 + threadIdx.x;  // 2048*32
  int s = idx >> 5, j = idx & 31;
  float freq = expf(-0.28782313714981824f * (float)j);
  float ang = (float)s * freq;
  rtab[idx] = make_float2(sinf(ang), cosf(ang));
}

// ---------------- GEMM: C[8192,1024] = A(bf16) @ W, B given as WT[n][k] ----
template <int MODE>
__global__ __launch_bounds__(256) void gemm_k(
    const unsigned short* __restrict__ A, const unsigned short* __restrict__ WT,
    void* __restrict__ outp, const float2* __restrict__ rtab) {
  __shared__ unsigned short At[128 * 64];
  __shared__ unsigned short Bt[128 * 64];
  const int tid = threadIdx.x;
  const int w = tid >> 6, lane = tid & 63, g = lane >> 4, c = lane & 15;
  const int wr = w >> 1, wc = w & 1;
  const int m0 = blockIdx.x * 128, n0 = blockIdx.y * 128;

  f32x4 zero = {0.f, 0.f, 0.f, 0.f};
  f32x4 acc[4][4];
#pragma unroll
  for (int i = 0; i < 4; ++i)
#pragma unroll
    for (int j = 0; j < 4; ++j) acc[i][j] = zero;

  for (int k0 = 0; k0 < 1024; k0 += 64) {
#pragma unroll
    for (int p = 0; p < 4; ++p) {
      int i = p * 256 + tid;
      int row = i >> 3, ls = i & 7;
      size_t off = ((size_t)(m0 + row) * 1024 + k0) * 2 + ((ls ^ (row & 7)) << 4);
      gll16((const char*)A + off, (char*)At + p * 4096 + w * 1024);
      size_t offb = ((size_t)(n0 + row) * 1024 + k0) * 2 + ((ls ^ (row & 7)) << 4);
      gll16((const char*)WT + offb, (char*)Bt + p * 4096 + w * 1024);
    }
    __syncthreads();
#pragma unroll
    for (int ks = 0; ks < 2; ++ks) {
      bf16x8 af[4], bfv[4];
#pragma unroll
      for (int am = 0; am < 4; ++am) {
        int row = wr * 64 + am * 16 + c;
        af[am] = *(const bf16x8*)(At + row * 64 + ((((ks << 2) | g) ^ (row & 7)) << 3));
      }
#pragma unroll
      for (int bn = 0; bn < 4; ++bn) {
        int row = wc * 64 + bn * 16 + c;
        bfv[bn] = *(const bf16x8*)(Bt + row * 64 + ((((ks << 2) | g) ^ (row & 7)) << 3));
      }
#pragma unroll
      for (int am = 0; am < 4; ++am)
#pragma unroll
        for (int bn = 0; bn < 4; ++bn)
          acc[am][bn] = MFMA16(af[am], bfv[bn], acc[am][bn]);
    }
    __syncthreads();
  }

  if (MODE == 0 || MODE == 1) {
    unsigned short* outb = (unsigned short*)outp;
#pragma unroll
    for (int am = 0; am < 4; ++am)
#pragma unroll
      for (int bp = 0; bp < 2; ++bp) {
        int col = n0 + wc * 64 + bp * 16 + c;
        int h = col >> 6, j = col & 63;
#pragma unroll
        for (int r = 0; r < 4; ++r) {
          int row = m0 + wr * 64 + am * 16 + (g << 2) + r;
          int b = row >> 11, s = row & 2047;
          float x1 = acc[am][bp][r], x2 = acc[am][bp + 2][r];
          float2 sc = rtab[s * 32 + j];
          float o1 = sc.y * x1 - sc.x * x2;
          float o2 = sc.x * x1 + sc.y * x2;
          if (MODE == 0) {
            o1 *= 0.18033688011112042f;  // 0.125 * log2(e)
            o2 *= 0.18033688011112042f;
          }
          size_t base = (((size_t)(b * 16 + h)) * 2048 + s) * 64;
          outb[base + j] = f2bf(o1);
          outb[base + 32 + j] = f2bf(o2);
        }
      }
  } else if (MODE == 2) {
    unsigned short* outb = (unsigned short*)outp;
#pragma unroll
    for (int am = 0; am < 4; ++am)
#pragma unroll
      for (int bn = 0; bn < 4; ++bn) {
        int col = n0 + wc * 64 + bn * 16 + c;
        int h = col >> 6, d = col & 63;
        int row0 = m0 + wr * 64 + am * 16 + (g << 2);
        int b = row0 >> 11, s0 = row0 & 2047;
        uint2 u;
        u.x = pack2bf(acc[am][bn][0], acc[am][bn][1]);
        u.y = pack2bf(acc[am][bn][2], acc[am][bn][3]);
        *(uint2*)(outb + ((size_t)((b * 16 + h) * 64 + d)) * 2048 + s0) = u;
      }
  } else {
    float* outf = (float*)outp;
#pragma unroll
    for (int am = 0; am < 4; ++am)
#pragma unroll
      for (int bn = 0; bn < 4; ++bn)
#pragma unroll
        for (int r = 0; r < 4; ++r)
          outf[(size_t)(m0 + wr * 64 + am * 16 + (g << 2) + r) * 1024 +
               (n0 + wc * 64 + bn * 16 + c)] = acc[am][bn][r];
  }
}

// ---------------- flash attention (causal, barrier-free, L2-direct) --------
// Q,K: [BH][2048][64] bf16 (Q pre-scaled by 0.125*log2e); VT: [BH][64][2048]
// ctx: [B][S][H*64] bf16.
// NO LDS, NO barriers: each wave autonomous (32 q-rows), K/V fragments read
// directly from global (L2-resident; fragments verified identical to R5's
// staged LDS contents). Reductions via __shfl_xor(.,32) -- R6's self-aliased
// permlane32_swap reduce produced NaN (suspected same-register self-swap ->
// halfmax returned only the other half's max -> exp overflow).
// K loaded per-t (transient 16 regs); V issued after exp so pword conversion
// (~24 VALU ops) hides L1/L2 latency; persistent state ~50 VGPR, peak < 128.
__global__ __launch_bounds__(256, 4) void attn_k(
    const unsigned short* __restrict__ Q, const unsigned short* __restrict__ K,
    const unsigned short* __restrict__ VT, unsigned short* __restrict__ ctx) {
  const int fid = blockIdx.x + (blockIdx.y << 4);
  const int xcd = fid & 7, j = fid >> 3;
  const int bh = (xcd << 3) + (j >> 4);  // 8 heads per XCD (K/V L2-resident)
  const int T = 15 - (j & 15);           // descending: long tiles first

  const int tid = threadIdx.x;
  const int w = tid >> 6, lane = tid & 63;
  const int hi = lane >> 5, c5 = lane & 31;
  const int qw = T * 128 + w * 32;        // this wave's 32 q-rows
  const int myDiag = 2 * T + (w >> 1);    // wave's diagonal kv-step

  const unsigned short* Qbh = Q + (size_t)bh * 2048 * 64;
  const unsigned short* Kbh = K + (size_t)bh * 2048 * 64;
  const unsigned short* VTbh = VT + (size_t)bh * 64 * 2048;

  // Q fragment (B-operand): lane holds Q[qw+c5][kb*16 + hi*8 + j], j=0..7
  bf16x8 qf[4];
#pragma unroll
  for (int kb = 0; kb < 4; ++kb)
    qf[kb] = *(const bf16x8*)(Qbh + (size_t)(qw + c5) * 64 + kb * 16 + hi * 8);

  // per-lane row bases: K rows = kv (A-operand), VT rows = d
  const unsigned short* Krow0 = Kbh + (size_t)c5 * 64 + hi * 8;           // t=0
  const unsigned short* Krow1 = Kbh + (size_t)(32 + c5) * 64 + hi * 8;    // t=1
  const unsigned short* Vrow0 = VTbh + (size_t)c5 * 2048 + hi * 8;        // dt=0
  const unsigned short* Vrow1 = VTbh + (size_t)(32 + c5) * 2048 + hi * 8; // dt=1

  f32x16 zacc;
#pragma unroll
  for (int i = 0; i < 16; ++i) zacc[i] = 0.f;
  f32x16 oacc[2];
  oacc[0] = zacc; oacc[1] = zacc;
  float m_run = -1e30f, l_run = 0.f;

  for (int st = 0; st <= myDiag; ++st) {
    const int kv0 = st * 64;

    // ---- QK^T: K fragments per-t direct from L2 (transient regs) ----
    f32x16 sacc[2];
    __builtin_amdgcn_s_setprio(1);
    {
      const unsigned short* kp = Krow0 + (size_t)kv0 * 64;
      bf16x8 k0 = *(const bf16x8*)(kp);
      bf16x8 k1 = *(const bf16x8*)(kp + 16);
      bf16x8 k2 = *(const bf16x8*)(kp + 32);
      bf16x8 k3 = *(const bf16x8*)(kp + 48);
      sacc[0] = MFMA32(k0, qf[0], zacc);
      sacc[0] = MFMA32(k1, qf[1], sacc[0]);
      sacc[0] = MFMA32(k2, qf[2], sacc[0]);
      sacc[0] = MFMA32(k3, qf[3], sacc[0]);
    }
    {
      const unsigned short* kp = Krow1 + (size_t)kv0 * 64;
      bf16x8 k0 = *(const bf16x8*)(kp);
      bf16x8 k1 = *(const bf16x8*)(kp + 16);
      bf16x8 k2 = *(const bf16x8*)(kp + 32);
      bf16x8 k3 = *(const bf16x8*)(kp + 48);
      sacc[1] = MFMA32(k0, qf[0], zacc);
      sacc[1] = MFMA32(k1, qf[1], sacc[1]);
      sacc[1] = MFMA32(k2, qf[2], sacc[1]);
      sacc[1] = MFMA32(k3, qf[3], sacc[1]);
    }
    __builtin_amdgcn_s_setprio(0);

    // causal mask (wave's diagonal step only)
    if (st == myDiag) {
      const int q = qw + c5;
#pragma unroll
      for (int t = 0; t < 2; ++t) {
        const int kvb = kv0 + t * 32 + (hi << 2);
#pragma unroll
        for (int i = 0; i < 16; ++i) {
          int kv = kvb + (i & 3) + ((i >> 2) << 3);
          if (kv > q) sacc[t][i] = -1e30f;
        }
      }
    }

    // ---- online softmax: q lane-local; cross-half reduce via shfl_xor ----
    float vmax = fmaxf(sacc[0][0], sacc[0][1]);
#pragma unroll
    for (int t = 0; t < 2; ++t)
#pragma unroll
      for (int i = (t == 0 ? 2 : 0); i < 16; i += 2)
        vmax = fmaxf(vmax, fmaxf(sacc[t][i], sacc[t][i + 1]));  // v_max3
    vmax = fmaxf(vmax, __shfl_xor(vmax, 32, 64));
    if (!__all(vmax <= m_run + 8.0f)) {  // defer-max (log2 domain, THR=8)
      float m_new = fmaxf(m_run, vmax);
      float alpha = exp2f(m_run - m_new);
      l_run *= alpha;
#pragma unroll
      for (int i = 0; i < 16; ++i) {
        oacc[0][i] *= alpha;
        oacc[1][i] *= alpha;
      }
      m_run = m_new;
    }
    float psum = 0.f;
#pragma unroll
    for (int t = 0; t < 2; ++t)
#pragma unroll
      for (int i = 0; i < 16; ++i) {
        float pv = exp2f(sacc[t][i] - m_run);
        sacc[t][i] = pv;
        psum += pv;
      }
    psum += __shfl_xor(psum, 32, 64);
    l_run += psum;

    // ---- V fragments issued now; pword conversion hides their latency ----
    bf16x8 vf[2][4];
#pragma unroll
    for (int kb = 0; kb < 4; ++kb) {
      vf[0][kb] = *(const bf16x8*)(Vrow0 + kv0 + kb * 16);
      vf[1][kb] = *(const bf16x8*)(Vrow1 + kv0 + kb * 16);
    }

    // ---- P -> bf16 PV B-fragments: 16 cvt_pk + 8 permlane32_swap ----
    unsigned pword[4][4];  // [kb][word]
#pragma unroll
    for (int t = 0; t < 2; ++t) {
      unsigned X[4][2];
#pragma unroll
      for (int u = 0; u < 4; ++u)
#pragma unroll
        for (int wp = 0; wp < 2; ++wp)
          X[u][wp] = cvtpk(sacc[t][u * 4 + 2 * wp], sacc[t][u * 4 + 2 * wp + 1]);
#pragma unroll
      for (int par = 0; par < 2; ++par) {
        const int kb = 2 * t + par;
#pragma unroll
        for (int wp = 0; wp < 2; ++wp) {
          unsigned a = X[2 * par][wp], b2 = X[2 * par + 1][wp];
          pl32swap(a, b2);
          pword[kb][wp] = a;
          pword[kb][wp + 2] = b2;
        }
      }
    }

    // ---- PV: O^T[d][q] += V^T[d][kv] . P[kv][q] ----
    __builtin_amdgcn_s_setprio(1);
#pragma unroll
    for (int kb = 0; kb < 4; ++kb) {
      union { unsigned u[4]; bf16x8 v; } pw;
#pragma unroll
      for (int k2 = 0; k2 < 4; ++k2) pw.u[k2] = pword[kb][k2];
      oacc[0] = MFMA32(vf[0][kb], pw.v, oacc[0]);
      oacc[1] = MFMA32(vf[1][kb], pw.v, oacc[1]);
    }
    __builtin_amdgcn_s_setprio(0);
  }

  // epilogue: O^T[d][q] / l -> ctx[b][q][h*64+d]
  const int b = bh >> 4, h = bh & 15;
  const float linv = 1.f / l_run;
  unsigned short* crow = ctx + ((size_t)(b * 2048 + qw + c5)) * 1024 + h * 64;
#pragma unroll
  for (int dt = 0; dt < 2; ++dt)
#pragma unroll
    for (int u = 0; u < 4; ++u) {
      int d0 = dt * 32 + 8 * u + 4 * hi;
      uint2 o;
      o.x = cvtpk(oacc[dt][4 * u] * linv, oacc[dt][4 * u + 1] * linv);
      o.y = cvtpk(oacc[dt][4 * u + 2] * linv, oacc[dt][4 * u + 3] * linv);
      *(uint2*)(crow + d0) = o;
    }
}

// ---------------- launcher ----------------

extern "C" void kernel_launch(void* const* d_in, const int* in_sizes, int n_in,
                              void* d_out, int out_size, void* d_ws, size_t ws_size,
                              hipStream_t stream) {
  (void)in_sizes; (void)n_in; (void)out_size; (void)ws_size;
  const float* x = (const float*)d_in[0];
  const float* Wq = (const float*)d_in[1];
  const float* Wk = (const float*)d_in[2];
  const float* Wv = (const float*)d_in[3];
  const float* Wo = (const float*)d_in[4];
  char* ws = (char*)d_ws;
  const size_t MiB = 1024 * 1024;
  unsigned short* xb  = (unsigned short*)(ws);             // 16 MiB
  unsigned short* WTq = (unsigned short*)(ws + 16 * MiB);  // 2 MiB each
  unsigned short* WTk = (unsigned short*)(ws + 18 * MiB);
  unsigned short* WTv = (unsigned short*)(ws + 20 * MiB);
  unsigned short* WTo = (unsigned short*)(ws + 22 * MiB);
  unsigned short* Qb  = (unsigned short*)(ws + 24 * MiB);  // 16 MiB each
  unsigned short* Kb  = (unsigned short*)(ws + 40 * MiB);
  unsigned short* VTb = (unsigned short*)(ws + 56 * MiB);
  unsigned short* ctx = (unsigned short*)(ws + 72 * MiB);
  float2* rtab = (float2*)(ws + 88 * MiB);                 // 512 KiB

  conv_x_k<<<8192, 256, 0, stream>>>(x, xb);
  transp_k<<<dim3(16, 16, 4), 256, 0, stream>>>(Wq, Wk, Wv, Wo, WTq, WTk, WTv, WTo);
  rope_k<<<256, 256, 0, stream>>>(rtab);
  gemm_k<0><<<dim3(64, 8), 256, 0, stream>>>(xb, WTq, Qb, rtab);
  gemm_k<1><<<dim3(64, 8), 256, 0, stream>>>(xb, WTk, Kb, rtab);
  gemm_k<2><<<dim3(64, 8), 256, 0, stream>>>(xb, WTv, VTb, rtab);
  attn_k<<<dim3(16, 64), 256, 0, stream>>>(Qb, Kb, VTb, ctx);
  gemm_k<3><<<dim3(64, 8), 256, 0, stream>>>(ctx, WTo, d_out, rtab);
}

// Round 9
// 205.680 us; speedup vs baseline: 1.6770x; 1.6770x over previous
//
#include <hip/hip_runtime.h>

#define DEVFN __device__ __forceinline__

typedef __attribute__((ext_vector_type(8))) short bf16x8;
typedef __attribute__((ext_vector_type(4))) float f32x4;
typedef __attribute__((ext_vector_type(16))) float f32x16;

#define MFMA16(a, b, c) __builtin_amdgcn_mfma_f32_16x16x32_bf16(a, b, c, 0, 0, 0)
#define MFMA32(a, b, c) __builtin_amdgcn_mfma_f32_32x32x16_bf16(a, b, c, 0, 0, 0)

DEVFN unsigned short f2bf(float f) {
  union { float f; unsigned u; } v; v.f = f;
  unsigned r = v.u + 0x7FFFu + ((v.u >> 16) & 1u);
  return (unsigned short)(r >> 16);
}
DEVFN unsigned pack2bf(float a, float b) {
  return (unsigned)f2bf(a) | ((unsigned)f2bf(b) << 16);
}
DEVFN unsigned cvtpk(float lo, float hi) {
  unsigned r;
  asm("v_cvt_pk_bf16_f32 %0, %1, %2" : "=v"(r) : "v"(lo), "v"(hi));
  return r;
}
DEVFN void pl32swap(unsigned& a, unsigned& b) {
  asm("v_permlane32_swap_b32 %0, %1" : "+v"(a), "+v"(b));
}
DEVFN void gll16(const void* g, void* l) {
  __builtin_amdgcn_global_load_lds((__attribute__((address_space(1))) void*)g,
                                   (__attribute__((address_space(3))) void*)l,
                                   16, 0, 0);
}

// ---------------- precompute kernels ----------------

__global__ __launch_bounds__(256) void conv_x_k(const float* __restrict__ x,
                                                unsigned short* __restrict__ xb) {
  int i = (blockIdx.x * 256 + threadIdx.x) * 4;
  float4 v = *(const float4*)(x + i);
  uint2 u;
  u.x = pack2bf(v.x, v.y);
  u.y = pack2bf(v.z, v.w);
  *(uint2*)(xb + i) = u;
}

// WT[n][k] = (bf16) W[k][n], 64x64 tiles through LDS
__global__ __launch_bounds__(256) void transp_k(
    const float* __restrict__ Wq, const float* __restrict__ Wk,
    const float* __restrict__ Wv, const float* __restrict__ Wo,
    unsigned short* __restrict__ Tq, unsigned short* __restrict__ Tk,
    unsigned short* __restrict__ Tv, unsigned short* __restrict__ To) {
  __shared__ unsigned short t[64 * 65];
  int z = blockIdx.z;
  const float* src = (z == 0) ? Wq : (z == 1) ? Wk : (z == 2) ? Wv : Wo;
  unsigned short* dst = (z == 0) ? Tq : (z == 1) ? Tk : (z == 2) ? Tv : To;
  int k0 = blockIdx.x * 64, n0 = blockIdx.y * 64;
  int tid = threadIdx.x;
#pragma unroll
  for (int i = 0; i < 16; ++i) {
    int flat = i * 256 + tid;
    int r = flat >> 6, cc = flat & 63;
    t[cc * 65 + r] = f2bf(src[(size_t)(k0 + r) * 1024 + n0 + cc]);
  }
  __syncthreads();
#pragma unroll
  for (int i = 0; i < 16; ++i) {
    int flat = i * 256 + tid;
    int rr = flat >> 6, cc = flat & 63;
    dst[(size_t)(n0 + rr) * 1024 + k0 + cc] = t[rr * 65 + cc];
  }
}

__global__ __launch_bounds__(256) void rope_k(float2* __restrict__ rtab) {
  int idx = blockIdx.x * 256 + threadIdx.x;  // 2048*32
  int s = idx >> 5, j = idx & 31;
  float freq = expf(-0.28782313714981824f * (float)j);
  float ang = (float)s * freq;
  rtab[idx] = make_float2(sinf(ang), cosf(ang));
}

// ---------------- GEMM: C[8192,1024] = A(bf16) @ W, B given as WT[n][k] ----
template <int MODE>
__global__ __launch_bounds__(256) void gemm_k(
    const unsigned short* __restrict__ A, const unsigned short* __restrict__ WT,
    void* __restrict__ outp, const float2* __restrict__ rtab) {
  __shared__ unsigned short At[128 * 64];
  __shared__ unsigned short Bt[128 * 64];
  const int tid = threadIdx.x;
  const int w = tid >> 6, lane = tid & 63, g = lane >> 4, c = lane & 15;
  const int wr = w >> 1, wc = w & 1;
  const int m0 = blockIdx.x * 128, n0 = blockIdx.y * 128;

  f32x4 zero = {0.f, 0.f, 0.f, 0.f};
  f32x4 acc[4][4];
#pragma unroll
  for (int i = 0; i < 4; ++i)
#pragma unroll
    for (int j = 0; j < 4; ++j) acc[i][j] = zero;

  for (int k0 = 0; k0 < 1024; k0 += 64) {
#pragma unroll
    for (int p = 0; p < 4; ++p) {
      int i = p * 256 + tid;
      int row = i >> 3, ls = i & 7;
      size_t off = ((size_t)(m0 + row) * 1024 + k0) * 2 + ((ls ^ (row & 7)) << 4);
      gll16((const char*)A + off, (char*)At + p * 4096 + w * 1024);
      size_t offb = ((size_t)(n0 + row) * 1024 + k0) * 2 + ((ls ^ (row & 7)) << 4);
      gll16((const char*)WT + offb, (char*)Bt + p * 4096 + w * 1024);
    }
    __syncthreads();
#pragma unroll
    for (int ks = 0; ks < 2; ++ks) {
      bf16x8 af[4], bfv[4];
#pragma unroll
      for (int am = 0; am < 4; ++am) {
        int row = wr * 64 + am * 16 + c;
        af[am] = *(const bf16x8*)(At + row * 64 + ((((ks << 2) | g) ^ (row & 7)) << 3));
      }
#pragma unroll
      for (int bn = 0; bn < 4; ++bn) {
        int row = wc * 64 + bn * 16 + c;
        bfv[bn] = *(const bf16x8*)(Bt + row * 64 + ((((ks << 2) | g) ^ (row & 7)) << 3));
      }
#pragma unroll
      for (int am = 0; am < 4; ++am)
#pragma unroll
        for (int bn = 0; bn < 4; ++bn)
          acc[am][bn] = MFMA16(af[am], bfv[bn], acc[am][bn]);
    }
    __syncthreads();
  }

  if (MODE == 0 || MODE == 1) {
    unsigned short* outb = (unsigned short*)outp;
#pragma unroll
    for (int am = 0; am < 4; ++am)
#pragma unroll
      for (int bp = 0; bp < 2; ++bp) {
        int col = n0 + wc * 64 + bp * 16 + c;
        int h = col >> 6, j = col & 63;
#pragma unroll
        for (int r = 0; r < 4; ++r) {
          int row = m0 + wr * 64 + am * 16 + (g << 2) + r;
          int b = row >> 11, s = row & 2047;
          float x1 = acc[am][bp][r], x2 = acc[am][bp + 2][r];
          float2 sc = rtab[s * 32 + j];
          float o1 = sc.y * x1 - sc.x * x2;
          float o2 = sc.x * x1 + sc.y * x2;
          if (MODE == 0) {
            o1 *= 0.18033688011112042f;  // 0.125 * log2(e)
            o2 *= 0.18033688011112042f;
          }
          size_t base = (((size_t)(b * 16 + h)) * 2048 + s) * 64;
          outb[base + j] = f2bf(o1);
          outb[base + 32 + j] = f2bf(o2);
        }
      }
  } else if (MODE == 2) {
    unsigned short* outb = (unsigned short*)outp;
#pragma unroll
    for (int am = 0; am < 4; ++am)
#pragma unroll
      for (int bn = 0; bn < 4; ++bn) {
        int col = n0 + wc * 64 + bn * 16 + c;
        int h = col >> 6, d = col & 63;
        int row0 = m0 + wr * 64 + am * 16 + (g << 2);
        int b = row0 >> 11, s0 = row0 & 2047;
        uint2 u;
        u.x = pack2bf(acc[am][bn][0], acc[am][bn][1]);
        u.y = pack2bf(acc[am][bn][2], acc[am][bn][3]);
        *(uint2*)(outb + ((size_t)((b * 16 + h) * 64 + d)) * 2048 + s0) = u;
      }
  } else {
    float* outf = (float*)outp;
#pragma unroll
    for (int am = 0; am < 4; ++am)
#pragma unroll
      for (int bn = 0; bn < 4; ++bn)
#pragma unroll
        for (int r = 0; r < 4; ++r)
          outf[(size_t)(m0 + wr * 64 + am * 16 + (g << 2) + r) * 1024 +
               (n0 + wc * 64 + bn * 16 + c)] = acc[am][bn][r];
  }
}

// ---------------- flash attention (causal, 32x32 MFMA, in-reg softmax) -----
// Q,K: [BH][2048][64] bf16 (Q pre-scaled by 0.125*log2e); VT: [BH][64][2048]
// ctx: [B][S][H*64] bf16.
// Paired-tile blocks (R3 structure: tiles p and 31-p share staged K/V,
// uniform 33 compute-units/block, 4 blocks/CU). LDS tiles row-major
// [64 rows][8 chunks of 16B] with XOR chunk swizzle (chunkpos = chunk ^
// (row&7)): staging is LINE-COALESCED (8 lanes/row, 8 lines per gll16 --
// slot-major staging was a 64-line gather per gll16, the R3/R5/R7 latency
// killer); fragment reads 4-way bank-aliased (acceptable, off critical
// path). Softmax q-lane-local; shfl_xor cross-half reduce; defer-max;
// P->PV frags via cvt_pk + permlane32_swap.
__global__ __launch_bounds__(256, 4) void attn_k(
    const unsigned short* __restrict__ Q, const unsigned short* __restrict__ K,
    const unsigned short* __restrict__ VT, unsigned short* __restrict__ ctx) {
  __shared__ unsigned short Kt[2][64 * 64];  // [row][chunkpos(16B)] swizzled
  __shared__ unsigned short Vt[2][64 * 64];

  const int fid = blockIdx.x + (blockIdx.y << 4);
  const int xcd = fid & 7, j = fid >> 3;
  const int bh = (xcd << 3) + (j >> 4);  // 8 heads per XCD (K/V L2-resident)
  const int p = j & 15;
  const int qtB = 31 - p;

  const int tid = threadIdx.x;
  const int w = tid >> 6, lane = tid & 63;
  const int hi = lane >> 5, c5 = lane & 31;
  const int myIsB = ((w >> 1) == (fid & 1));
  const int myTile = myIsB ? qtB : p;      // 64-row q-tile; also diagonal step
  const int qw = myTile * 64 + (w & 1) * 32;  // this wave's 32 q-rows

  const unsigned short* Qbh = Q + (size_t)bh * 2048 * 64;
  const unsigned short* Kbh = K + (size_t)bh * 2048 * 64;
  const unsigned short* VTbh = VT + (size_t)bh * 64 * 2048;

  // Q fragment (B-operand): lane holds Q[qw+c5][kb*16 + hi*8 + j], j=0..7
  bf16x8 qf[4];
#pragma unroll
  for (int kb = 0; kb < 4; ++kb)
    qf[kb] = *(const bf16x8*)(Qbh + (size_t)(qw + c5) * 64 + kb * 16 + hi * 8);

  f32x16 zacc;
#pragma unroll
  for (int i = 0; i < 16; ++i) zacc[i] = 0.f;
  f32x16 oacc[2];
  oacc[0] = zacc; oacc[1] = zacc;
  float m_run = -1e30f, l_run = 0.f;

  // staging: lane l covers (row = g*8 + (l>>3), chunkpos = l&7) which holds
  // global chunk (l&7) ^ (row&7)  [inverse-swizzled source, T21]
  const int row8 = lane >> 3;
  const int csw = (lane & 7) ^ row8;
  auto stage = [&](int st, int buf) {
#pragma unroll
    for (int pp = 0; pp < 2; ++pp) {
      const int g = pp * 4 + w;
      const int krow = g * 8 + row8;
      gll16((const char*)Kbh + (size_t)(st * 64 + krow) * 128 + csw * 16,
            (char*)(&Kt[buf][0]) + g * 1024);
      gll16((const char*)VTbh + (size_t)krow * 4096 + (size_t)st * 128 + csw * 16,
            (char*)(&Vt[buf][0]) + g * 1024);
    }
  };

  stage(0, 0);
  __syncthreads();

  for (int st = 0; st <= qtB; ++st) {
    const int cur = st & 1;
    if (st < qtB) stage(st + 1, cur ^ 1);

    if (st <= myTile) {
      const unsigned short* Kb_ = &Kt[cur][0];
      const unsigned short* Vb_ = &Vt[cur][0];
      const int kv0 = st * 64;
      const int cx = c5 & 7;  // row&7 for this lane's fragment rows

      // QK^T: sacc[t] = S^T[kv = kv0 + t*32 + (reg map)][q = qw + c5]
      f32x16 sacc[2];
      __builtin_amdgcn_s_setprio(1);
#pragma unroll
      for (int t = 0; t < 2; ++t) {
        const int ro = (t * 32 + c5) * 64;
        bf16x8 kf0 = *(const bf16x8*)(Kb_ + ro + ((hi ^ cx) << 3));
        sacc[t] = MFMA32(kf0, qf[0], zacc);
#pragma unroll
        for (int kb = 1; kb < 4; ++kb) {
          bf16x8 kf = *(const bf16x8*)(Kb_ + ro + (((2 * kb + hi) ^ cx) << 3));
          sacc[t] = MFMA32(kf, qf[kb], sacc[t]);
        }
      }
      __builtin_amdgcn_s_setprio(0);

      // causal mask (wave's diagonal step only)
      if (st == myTile) {
        const int q = qw + c5;
#pragma unroll
        for (int t = 0; t < 2; ++t) {
          const int kvb = kv0 + t * 32 + (hi << 2);
#pragma unroll
          for (int i = 0; i < 16; ++i) {
            int kv = kvb + (i & 3) + ((i >> 2) << 3);
            if (kv > q) sacc[t][i] = -1e30f;
          }
        }
      }

      // online softmax: q lane-local; cross-half reduce via shfl_xor
      float vmax = fmaxf(sacc[0][0], sacc[0][1]);
#pragma unroll
      for (int t = 0; t < 2; ++t)
#pragma unroll
        for (int i = (t == 0 ? 2 : 0); i < 16; i += 2)
          vmax = fmaxf(vmax, fmaxf(sacc[t][i], sacc[t][i + 1]));  // v_max3
      vmax = fmaxf(vmax, __shfl_xor(vmax, 32, 64));
      if (!__all(vmax <= m_run + 8.0f)) {  // defer-max (log2 domain, THR=8)
        float m_new = fmaxf(m_run, vmax);
        float alpha = exp2f(m_run - m_new);
        l_run *= alpha;
#pragma unroll
        for (int i = 0; i < 16; ++i) {
          oacc[0][i] *= alpha;
          oacc[1][i] *= alpha;
        }
        m_run = m_new;
      }
      float psum = 0.f;
#pragma unroll
      for (int t = 0; t < 2; ++t)
#pragma unroll
        for (int i = 0; i < 16; ++i) {
          float pv = exp2f(sacc[t][i] - m_run);
          sacc[t][i] = pv;
          psum += pv;
        }
      psum += __shfl_xor(psum, 32, 64);
      l_run += psum;

      // P -> bf16 PV B-fragments in-register: 16 cvt_pk + 8 permlane32_swap
      unsigned pword[4][4];  // [kb][word]
#pragma unroll
      for (int t = 0; t < 2; ++t) {
        unsigned X[4][2];
#pragma unroll
        for (int u = 0; u < 4; ++u)
#pragma unroll
          for (int wp = 0; wp < 2; ++wp)
            X[u][wp] = cvtpk(sacc[t][u * 4 + 2 * wp], sacc[t][u * 4 + 2 * wp + 1]);
#pragma unroll
        for (int par = 0; par < 2; ++par) {
          const int kb = 2 * t + par;
#pragma unroll
          for (int wp = 0; wp < 2; ++wp) {
            unsigned a = X[2 * par][wp], b2 = X[2 * par + 1][wp];
            pl32swap(a, b2);
            pword[kb][wp] = a;
            pword[kb][wp + 2] = b2;
          }
        }
      }

      // PV: O^T[d][q] += V^T[d][kv] . P[kv][q]
      __builtin_amdgcn_s_setprio(1);
#pragma unroll
      for (int kb = 0; kb < 4; ++kb) {
        union { unsigned u[4]; bf16x8 v; } pw;
#pragma unroll
        for (int k2 = 0; k2 < 4; ++k2) pw.u[k2] = pword[kb][k2];
        const int cp = ((2 * kb + hi) ^ cx) << 3;
#pragma unroll
        for (int dt = 0; dt < 2; ++dt) {
          bf16x8 vf = *(const bf16x8*)(Vb_ + (dt * 32 + c5) * 64 + cp);
          oacc[dt] = MFMA32(vf, pw.v, oacc[dt]);
        }
      }
      __builtin_amdgcn_s_setprio(0);
    }
    __syncthreads();
  }

  // epilogue: O^T[d][q] / l -> ctx[b][q][h*64+d]
  const int b = bh >> 4, h = bh & 15;
  const float linv = 1.f / l_run;
  unsigned short* crow = ctx + ((size_t)(b * 2048 + qw + c5)) * 1024 + h * 64;
#pragma unroll
  for (int dt = 0; dt < 2; ++dt)
#pragma unroll
    for (int u = 0; u < 4; ++u) {
      int d0 = dt * 32 + 8 * u + 4 * hi;
      uint2 o;
      o.x = cvtpk(oacc[dt][4 * u] * linv, oacc[dt][4 * u + 1] * linv);
      o.y = cvtpk(oacc[dt][4 * u + 2] * linv, oacc[dt][4 * u + 3] * linv);
      *(uint2*)(crow + d0) = o;
    }
}

// ---------------- launcher ----------------

extern "C" void kernel_launch(void* const* d_in, const int* in_sizes, int n_in,
                              void* d_out, int out_size, void* d_ws, size_t ws_size,
                              hipStream_t stream) {
  (void)in_sizes; (void)n_in; (void)out_size; (void)ws_size;
  const float* x = (const float*)d_in[0];
  const float* Wq = (const float*)d_in[1];
  const float* Wk = (const float*)d_in[2];
  const float* Wv = (const float*)d_in[3];
  const float* Wo = (const float*)d_in[4];
  char* ws = (char*)d_ws;
  const size_t MiB = 1024 * 1024;
  unsigned short* xb  = (unsigned short*)(ws);             // 16 MiB
  unsigned short* WTq = (unsigned short*)(ws + 16 * MiB);  // 2 MiB each
  unsigned short* WTk = (unsigned short*)(ws + 18 * MiB);
  unsigned short* WTv = (unsigned short*)(ws + 20 * MiB);
  unsigned short* WTo = (unsigned short*)(ws + 22 * MiB);
  unsigned short* Qb  = (unsigned short*)(ws + 24 * MiB);  // 16 MiB each
  unsigned short* Kb  = (unsigned short*)(ws + 40 * MiB);
  unsigned short* VTb = (unsigned short*)(ws + 56 * MiB);
  unsigned short* ctx = (unsigned short*)(ws + 72 * MiB);
  float2* rtab = (float2*)(ws + 88 * MiB);                 // 512 KiB

  conv_x_k<<<8192, 256, 0, stream>>>(x, xb);
  transp_k<<<dim3(16, 16, 4), 256, 0, stream>>>(Wq, Wk, Wv, Wo, WTq, WTk, WTv, WTo);
  rope_k<<<256, 256, 0, stream>>>(rtab);
  gemm_k<0><<<dim3(64, 8), 256, 0, stream>>>(xb, WTq, Qb, rtab);
  gemm_k<1><<<dim3(64, 8), 256, 0, stream>>>(xb, WTk, Kb, rtab);
  gemm_k<2><<<dim3(64, 8), 256, 0, stream>>>(xb, WTv, VTb, rtab);
  attn_k<<<dim3(16, 64), 256, 0, stream>>>(Qb, Kb, VTb, ctx);
  gemm_k<3><<<dim3(64, 8), 256, 0, stream>>>(ctx, WTo, d_out, rtab);
}

// Round 10
// 184.621 us; speedup vs baseline: 1.8683x; 1.1141x over previous
//
#include <hip/hip_runtime.h>

#define DEVFN __device__ __forceinline__

typedef __attribute__((ext_vector_type(8))) short bf16x8;
typedef __attribute__((ext_vector_type(4))) float f32x4;
typedef __attribute__((ext_vector_type(16))) float f32x16;

#define MFMA16(a, b, c) __builtin_amdgcn_mfma_f32_16x16x32_bf16(a, b, c, 0, 0, 0)
#define MFMA32(a, b, c) __builtin_amdgcn_mfma_f32_32x32x16_bf16(a, b, c, 0, 0, 0)

DEVFN unsigned short f2bf(float f) {
  union { float f; unsigned u; } v; v.f = f;
  unsigned r = v.u + 0x7FFFu + ((v.u >> 16) & 1u);
  return (unsigned short)(r >> 16);
}
DEVFN unsigned pack2bf(float a, float b) {
  return (unsigned)f2bf(a) | ((unsigned)f2bf(b) << 16);
}
DEVFN unsigned cvtpk(float lo, float hi) {
  unsigned r;
  asm("v_cvt_pk_bf16_f32 %0, %1, %2" : "=v"(r) : "v"(lo), "v"(hi));
  return r;
}
DEVFN void pl32swap(unsigned& a, unsigned& b) {
  asm("v_permlane32_swap_b32 %0, %1" : "+v"(a), "+v"(b));
}
DEVFN void gll16(const void* g, void* l) {
  __builtin_amdgcn_global_load_lds((__attribute__((address_space(1))) void*)g,
                                   (__attribute__((address_space(3))) void*)l,
                                   16, 0, 0);
}

// ---------------- precompute kernels ----------------

__global__ __launch_bounds__(256) void conv_x_k(const float* __restrict__ x,
                                                unsigned short* __restrict__ xb) {
  int i = (blockIdx.x * 256 + threadIdx.x) * 4;
  float4 v = *(const float4*)(x + i);
  uint2 u;
  u.x = pack2bf(v.x, v.y);
  u.y = pack2bf(v.z, v.w);
  *(uint2*)(xb + i) = u;
}

// WT[n][k] = (bf16) W[k][n], 64x64 tiles through LDS
__global__ __launch_bounds__(256) void transp_k(
    const float* __restrict__ Wq, const float* __restrict__ Wk,
    const float* __restrict__ Wv, const float* __restrict__ Wo,
    unsigned short* __restrict__ Tq, unsigned short* __restrict__ Tk,
    unsigned short* __restrict__ Tv, unsigned short* __restrict__ To) {
  __shared__ unsigned short t[64 * 65];
  int z = blockIdx.z;
  const float* src = (z == 0) ? Wq : (z == 1) ? Wk : (z == 2) ? Wv : Wo;
  unsigned short* dst = (z == 0) ? Tq : (z == 1) ? Tk : (z == 2) ? Tv : To;
  int k0 = blockIdx.x * 64, n0 = blockIdx.y * 64;
  int tid = threadIdx.x;
#pragma unroll
  for (int i = 0; i < 16; ++i) {
    int flat = i * 256 + tid;
    int r = flat >> 6, cc = flat & 63;
    t[cc * 65 + r] = f2bf(src[(size_t)(k0 + r) * 1024 + n0 + cc]);
  }
  __syncthreads();
#pragma unroll
  for (int i = 0; i < 16; ++i) {
    int flat = i * 256 + tid;
    int rr = flat >> 6, cc = flat & 63;
    dst[(size_t)(n0 + rr) * 1024 + k0 + cc] = t[rr * 65 + cc];
  }
}

__global__ __launch_bounds__(256) void rope_k(float2* __restrict__ rtab) {
  int idx = blockIdx.x * 256 + threadIdx.x;  // 2048*32
  int s = idx >> 5, j = idx & 31;
  float freq = expf(-0.28782313714981824f * (float)j);
  float ang = (float)s * freq;
  rtab[idx] = make_float2(sinf(ang), cosf(ang));
}

// ---------------- GEMM: C[8192,1024] = A(bf16) @ W, B given as WT[n][k] ----
// MODE 0: Q epilogue (RoPE + 0.125*log2e) -> [BH][S][64] row-major
// MODE 1: K epilogue (RoPE) -> FRAGMENT-LINEAR Kf:
//   ushort off = bh*131072 + (s>>5)*2048 + kb*512 + (hi*32 + (s&31))*8 + el
//   where kb=d>>4, hi=(d>>3)&1, el=d&7  (lane-contiguous 16B per lane)
// MODE 2: V epilogue -> FRAGMENT-LINEAR Vf:
//   ushort off = bh*131072 + (s>>6)*4096 + ((s>>4)&3)*1024 + (d>>5)*512
//              + (((s>>3)&1)*32 + (d&31))*8 + (s&7)
// MODE 3: plain fp32 -> d_out
template <int MODE>
__global__ __launch_bounds__(256) void gemm_k(
    const unsigned short* __restrict__ A, const unsigned short* __restrict__ WT,
    void* __restrict__ outp, const float2* __restrict__ rtab) {
  __shared__ unsigned short At[128 * 64];
  __shared__ unsigned short Bt[128 * 64];
  const int tid = threadIdx.x;
  const int w = tid >> 6, lane = tid & 63, g = lane >> 4, c = lane & 15;
  const int wr = w >> 1, wc = w & 1;
  const int m0 = blockIdx.x * 128, n0 = blockIdx.y * 128;

  f32x4 zero = {0.f, 0.f, 0.f, 0.f};
  f32x4 acc[4][4];
#pragma unroll
  for (int i = 0; i < 4; ++i)
#pragma unroll
    for (int j = 0; j < 4; ++j) acc[i][j] = zero;

  for (int k0 = 0; k0 < 1024; k0 += 64) {
#pragma unroll
    for (int p = 0; p < 4; ++p) {
      int i = p * 256 + tid;
      int row = i >> 3, ls = i & 7;
      size_t off = ((size_t)(m0 + row) * 1024 + k0) * 2 + ((ls ^ (row & 7)) << 4);
      gll16((const char*)A + off, (char*)At + p * 4096 + w * 1024);
      size_t offb = ((size_t)(n0 + row) * 1024 + k0) * 2 + ((ls ^ (row & 7)) << 4);
      gll16((const char*)WT + offb, (char*)Bt + p * 4096 + w * 1024);
    }
    __syncthreads();
#pragma unroll
    for (int ks = 0; ks < 2; ++ks) {
      bf16x8 af[4], bfv[4];
#pragma unroll
      for (int am = 0; am < 4; ++am) {
        int row = wr * 64 + am * 16 + c;
        af[am] = *(const bf16x8*)(At + row * 64 + ((((ks << 2) | g) ^ (row & 7)) << 3));
      }
#pragma unroll
      for (int bn = 0; bn < 4; ++bn) {
        int row = wc * 64 + bn * 16 + c;
        bfv[bn] = *(const bf16x8*)(Bt + row * 64 + ((((ks << 2) | g) ^ (row & 7)) << 3));
      }
#pragma unroll
      for (int am = 0; am < 4; ++am)
#pragma unroll
        for (int bn = 0; bn < 4; ++bn)
          acc[am][bn] = MFMA16(af[am], bfv[bn], acc[am][bn]);
    }
    __syncthreads();
  }

  if (MODE == 0) {
    unsigned short* outb = (unsigned short*)outp;
#pragma unroll
    for (int am = 0; am < 4; ++am)
#pragma unroll
      for (int bp = 0; bp < 2; ++bp) {
        int col = n0 + wc * 64 + bp * 16 + c;
        int h = col >> 6, j = col & 63;
#pragma unroll
        for (int r = 0; r < 4; ++r) {
          int row = m0 + wr * 64 + am * 16 + (g << 2) + r;
          int b = row >> 11, s = row & 2047;
          float x1 = acc[am][bp][r], x2 = acc[am][bp + 2][r];
          float2 sc = rtab[s * 32 + j];
          float o1 = (sc.y * x1 - sc.x * x2) * 0.18033688011112042f;
          float o2 = (sc.x * x1 + sc.y * x2) * 0.18033688011112042f;
          size_t base = (((size_t)(b * 16 + h)) * 2048 + s) * 64;
          outb[base + j] = f2bf(o1);
          outb[base + 32 + j] = f2bf(o2);
        }
      }
  } else if (MODE == 1) {
    unsigned short* outb = (unsigned short*)outp;
#pragma unroll
    for (int am = 0; am < 4; ++am)
#pragma unroll
      for (int bp = 0; bp < 2; ++bp) {
        int col = n0 + wc * 64 + bp * 16 + c;
        int h = col >> 6, j = col & 63;  // j in [0,32)
        const int kb = j >> 4, hil = (j >> 3) & 1, el = j & 7;
#pragma unroll
        for (int r = 0; r < 4; ++r) {
          int row = m0 + wr * 64 + am * 16 + (g << 2) + r;
          int b = row >> 11, s = row & 2047;
          float x1 = acc[am][bp][r], x2 = acc[am][bp + 2][r];
          float2 sc = rtab[s * 32 + j];
          float o1 = sc.y * x1 - sc.x * x2;
          float o2 = sc.x * x1 + sc.y * x2;
          size_t base = (size_t)(b * 16 + h) * 131072 + (size_t)(s >> 5) * 2048 +
                        (hil * 32 + (s & 31)) * 8 + el;
          outb[base + kb * 512] = f2bf(o1);
          outb[base + (kb + 2) * 512] = f2bf(o2);
        }
      }
  } else if (MODE == 2) {
    unsigned short* outb = (unsigned short*)outp;
#pragma unroll
    for (int am = 0; am < 4; ++am)
#pragma unroll
      for (int bn = 0; bn < 4; ++bn) {
        int col = n0 + wc * 64 + bn * 16 + c;
        int h = col >> 6, d = col & 63;
        int row0 = m0 + wr * 64 + am * 16 + (g << 2);
        int b = row0 >> 11, s0 = row0 & 2047;
        uint2 u;
        u.x = pack2bf(acc[am][bn][0], acc[am][bn][1]);
        u.y = pack2bf(acc[am][bn][2], acc[am][bn][3]);
        size_t off = (size_t)(b * 16 + h) * 131072 + (size_t)(s0 >> 6) * 4096 +
                     ((s0 >> 4) & 3) * 1024 + (d >> 5) * 512 +
                     (((s0 >> 3) & 1) * 32 + (d & 31)) * 8 + (s0 & 7);
        *(uint2*)(outb + off) = u;
      }
  } else {
    float* outf = (float*)outp;
#pragma unroll
    for (int am = 0; am < 4; ++am)
#pragma unroll
      for (int bn = 0; bn < 4; ++bn)
#pragma unroll
        for (int r = 0; r < 4; ++r)
          outf[(size_t)(m0 + wr * 64 + am * 16 + (g << 2) + r) * 1024 +
               (n0 + wc * 64 + bn * 16 + c)] = acc[am][bn][r];
  }
}

// ---------------- flash attention (causal, barrier-free, frag-linear) ------
// Q: [BH][2048][64] bf16 (pre-scaled 0.125*log2e). Kf/Vf: fragment-linear
// (see gemm_k MODE 1/2): every fragment load = one lane-contiguous 1KB
// global_load_dwordx4 (R7's direct loads were 64-line gathers; fixed here).
// NO LDS, NO barriers: wave = 32 q-rows, fully autonomous; processes units
// U then 63-U sequentially -> exactly 33 kv-steps/wave, zero tail, no convoy
// (R2/R3/R8 plateaued ~100us at ~50% barrier/lockstep stall).
// kf prefetched one step ahead (issued AFTER vf so PV's wait is a counted
// vmcnt, not a drain); vf latency hidden under softmax (T14).
__global__ __launch_bounds__(256, 2) void attn_k(
    const unsigned short* __restrict__ Q, const unsigned short* __restrict__ Kf,
    const unsigned short* __restrict__ Vf, unsigned short* __restrict__ ctx) {
  const int blk = blockIdx.x;               // 512 blocks
  const int xcd = blk & 7, idx = blk >> 3;  // 8 heads/XCD: K/V L2-resident
  const int bh = (xcd << 3) + (idx & 7);
  const int pbase = (idx >> 3) << 2;
  const int tid = threadIdx.x;
  const int w = tid >> 6, lane = tid & 63;
  const int hi = lane >> 5, c5 = lane & 31;
  const int P = pbase + w;  // 0..31; wave does units P and 63-P

  const unsigned short* Qbh = Q + (size_t)bh * 2048 * 64;
  const unsigned short* Kbh = Kf + (size_t)bh * 131072;
  const unsigned short* Vbh = Vf + (size_t)bh * 131072;
  const int b = bh >> 4, h = bh & 15;

  f32x16 zacc;
#pragma unroll
  for (int i = 0; i < 16; ++i) zacc[i] = 0.f;

  auto pass = [&](int U) {
    const int qw = U * 32;
    const int S = (U >> 1) + 1;  // steps 0..S-1; diagonal at S-1

    bf16x8 qf[4];
#pragma unroll
    for (int kb = 0; kb < 4; ++kb)
      qf[kb] = *(const bf16x8*)(Qbh + (size_t)(qw + c5) * 64 + kb * 16 + hi * 8);

    f32x16 oacc[2];
    oacc[0] = zacc; oacc[1] = zacc;
    float m_run = -1e30f, l_run = 0.f;

    // kf(t,kb) at step st: ushort off = st*4096 + t*2048 + kb*512 + lane*8
    bf16x8 kfc[2][4];
#pragma unroll
    for (int t = 0; t < 2; ++t)
#pragma unroll
      for (int kb = 0; kb < 4; ++kb)
        kfc[t][kb] = *(const bf16x8*)(Kbh + t * 2048 + kb * 512 + lane * 8);

    for (int st = 0; st < S; ++st) {
      // ---- QK^T ----
      f32x16 sacc[2];
      __builtin_amdgcn_s_setprio(1);
#pragma unroll
      for (int t = 0; t < 2; ++t) {
        sacc[t] = MFMA32(kfc[t][0], qf[0], zacc);
#pragma unroll
        for (int kb = 1; kb < 4; ++kb)
          sacc[t] = MFMA32(kfc[t][kb], qf[kb], sacc[t]);
      }
      __builtin_amdgcn_s_setprio(0);

      // ---- issue V loads (hidden under softmax), then next-K prefetch ----
      // vf(dt,kb): ushort off = st*4096 + kb*1024 + dt*512 + lane*8
      bf16x8 vfr[2][4];
#pragma unroll
      for (int kb = 0; kb < 4; ++kb)
#pragma unroll
        for (int dt = 0; dt < 2; ++dt)
          vfr[dt][kb] = *(const bf16x8*)(Vbh + (size_t)st * 4096 + kb * 1024 +
                                         dt * 512 + lane * 8);
      bf16x8 kfn[2][4];
      if (st + 1 < S) {
#pragma unroll
        for (int t = 0; t < 2; ++t)
#pragma unroll
          for (int kb = 0; kb < 4; ++kb)
            kfn[t][kb] = *(const bf16x8*)(Kbh + (size_t)(st + 1) * 4096 +
                                          t * 2048 + kb * 512 + lane * 8);
      }

      // ---- causal mask (diagonal step only) ----
      if (st == S - 1) {
        const int q = qw + c5;
#pragma unroll
        for (int t = 0; t < 2; ++t) {
          const int kvb = st * 64 + t * 32 + (hi << 2);
#pragma unroll
          for (int i = 0; i < 16; ++i) {
            int kv = kvb + (i & 3) + ((i >> 2) << 3);
            if (kv > q) sacc[t][i] = -1e30f;
          }
        }
      }

      // ---- online softmax (q lane-local) ----
      float vmax = fmaxf(sacc[0][0], sacc[0][1]);
#pragma unroll
      for (int t = 0; t < 2; ++t)
#pragma unroll
        for (int i = (t == 0 ? 2 : 0); i < 16; i += 2)
          vmax = fmaxf(vmax, fmaxf(sacc[t][i], sacc[t][i + 1]));  // v_max3
      vmax = fmaxf(vmax, __shfl_xor(vmax, 32, 64));
      if (!__all(vmax <= m_run + 8.0f)) {  // defer-max (log2 domain, THR=8)
        float m_new = fmaxf(m_run, vmax);
        float alpha = exp2f(m_run - m_new);
        l_run *= alpha;
#pragma unroll
        for (int i = 0; i < 16; ++i) {
          oacc[0][i] *= alpha;
          oacc[1][i] *= alpha;
        }
        m_run = m_new;
      }
      float psum = 0.f;
#pragma unroll
      for (int t = 0; t < 2; ++t)
#pragma unroll
        for (int i = 0; i < 16; ++i) {
          float pv = exp2f(sacc[t][i] - m_run);
          sacc[t][i] = pv;
          psum += pv;
        }
      psum += __shfl_xor(psum, 32, 64);
      l_run += psum;

      // ---- P -> bf16 PV B-fragments: 16 cvt_pk + 8 permlane32_swap ----
      unsigned pword[4][4];
#pragma unroll
      for (int t = 0; t < 2; ++t) {
        unsigned X[4][2];
#pragma unroll
        for (int u = 0; u < 4; ++u)
#pragma unroll
          for (int wp = 0; wp < 2; ++wp)
            X[u][wp] = cvtpk(sacc[t][u * 4 + 2 * wp], sacc[t][u * 4 + 2 * wp + 1]);
#pragma unroll
        for (int par = 0; par < 2; ++par) {
          const int kb = 2 * t + par;
#pragma unroll
          for (int wp = 0; wp < 2; ++wp) {
            unsigned a = X[2 * par][wp], b2 = X[2 * par + 1][wp];
            pl32swap(a, b2);
            pword[kb][wp] = a;
            pword[kb][wp + 2] = b2;
          }
        }
      }

      // ---- PV ----
      __builtin_amdgcn_s_setprio(1);
#pragma unroll
      for (int kb = 0; kb < 4; ++kb) {
        union { unsigned u[4]; bf16x8 v; } pw;
#pragma unroll
        for (int k2 = 0; k2 < 4; ++k2) pw.u[k2] = pword[kb][k2];
        oacc[0] = MFMA32(vfr[0][kb], pw.v, oacc[0]);
        oacc[1] = MFMA32(vfr[1][kb], pw.v, oacc[1]);
      }
      __builtin_amdgcn_s_setprio(0);

      // ---- rotate prefetched K ----
      if (st + 1 < S) {
#pragma unroll
        for (int t = 0; t < 2; ++t)
#pragma unroll
          for (int kb = 0; kb < 4; ++kb) kfc[t][kb] = kfn[t][kb];
      }
    }

    // ---- epilogue ----
    const float linv = 1.f / l_run;
    unsigned short* crow = ctx + ((size_t)(b * 2048 + qw + c5)) * 1024 + h * 64;
#pragma unroll
    for (int dt = 0; dt < 2; ++dt)
#pragma unroll
      for (int u = 0; u < 4; ++u) {
        int d0 = dt * 32 + 8 * u + 4 * hi;
        uint2 o;
        o.x = cvtpk(oacc[dt][4 * u] * linv, oacc[dt][4 * u + 1] * linv);
        o.y = cvtpk(oacc[dt][4 * u + 2] * linv, oacc[dt][4 * u + 3] * linv);
        *(uint2*)(crow + d0) = o;
      }
  };

  pass(P);
  pass(63 - P);
}

// ---------------- launcher ----------------

extern "C" void kernel_launch(void* const* d_in, const int* in_sizes, int n_in,
                              void* d_out, int out_size, void* d_ws, size_t ws_size,
                              hipStream_t stream) {
  (void)in_sizes; (void)n_in; (void)out_size; (void)ws_size;
  const float* x = (const float*)d_in[0];
  const float* Wq = (const float*)d_in[1];
  const float* Wk = (const float*)d_in[2];
  const float* Wv = (const float*)d_in[3];
  const float* Wo = (const float*)d_in[4];
  char* ws = (char*)d_ws;
  const size_t MiB = 1024 * 1024;
  unsigned short* xb  = (unsigned short*)(ws);             // 16 MiB
  unsigned short* WTq = (unsigned short*)(ws + 16 * MiB);  // 2 MiB each
  unsigned short* WTk = (unsigned short*)(ws + 18 * MiB);
  unsigned short* WTv = (unsigned short*)(ws + 20 * MiB);
  unsigned short* WTo = (unsigned short*)(ws + 22 * MiB);
  unsigned short* Qb  = (unsigned short*)(ws + 24 * MiB);  // 16 MiB each
  unsigned short* Kfb = (unsigned short*)(ws + 40 * MiB);
  unsigned short* Vfb = (unsigned short*)(ws + 56 * MiB);
  unsigned short* ctx = (unsigned short*)(ws + 72 * MiB);
  float2* rtab = (float2*)(ws + 88 * MiB);                 // 512 KiB

  conv_x_k<<<8192, 256, 0, stream>>>(x, xb);
  transp_k<<<dim3(16, 16, 4), 256, 0, stream>>>(Wq, Wk, Wv, Wo, WTq, WTk, WTv, WTo);
  rope_k<<<256, 256, 0, stream>>>(rtab);
  gemm_k<0><<<dim3(64, 8), 256, 0, stream>>>(xb, WTq, Qb, rtab);
  gemm_k<1><<<dim3(64, 8), 256, 0, stream>>>(xb, WTk, Kfb, rtab);
  gemm_k<2><<<dim3(64, 8), 256, 0, stream>>>(xb, WTv, Vfb, rtab);
  attn_k<<<512, 256, 0, stream>>>(Qb, Kfb, Vfb, ctx);
  gemm_k<3><<<dim3(64, 8), 256, 0, stream>>>(ctx, WTo, d_out, rtab);
}